// Round 1
// baseline (347.847 us; speedup 1.0000x reference)
//
#include <hip/hip_runtime.h>
#include <math.h>

#define BB 8
#define NN 100
#define KK 20
#define DD 256
#define MM 2000                    // NN*KK anchors per batch
#define TINV 10.0f                 // 1/TEMP
#define LOSS_SCALE 1.953125e-7f    // ALPHA / (B_NORM*N*K*D) = 0.1/512000

// ---------------- kernel 1: per-row inverse L2 norm ----------------
// one wave per row; 64 lanes x float4 = 256 elements
__global__ void norm_kernel(const float* __restrict__ x, float* __restrict__ invn) {
    const int row = blockIdx.x * 4 + (threadIdx.x >> 6);
    const int lane = threadIdx.x & 63;
    const float4 v = ((const float4*)(x + (size_t)row * DD))[lane];
    float s = v.x * v.x + v.y * v.y + v.z * v.z + v.w * v.w;
    #pragma unroll
    for (int o = 32; o >= 1; o >>= 1) s += __shfl_xor(s, o, 64);
    if (lane == 0) invn[row] = 1.0f / sqrtf(s);
}

// ---------------- kernel 2: fused Gram + exp-sum + intra-sum ----------------
// grid = 1024 blocks = 8 batches x 32 row-tiles x 4 col-quarters, 256 threads.
// Block computes rows [rbase,rbase+64) vs cols [quarter*512, +512), K=256 in
// 4 chunks of 64 staged k-major in LDS (conflict-free writes, b128 reads).
// Per-row partial exp-sums / intra-sums are atomically added to global.
__global__ __launch_bounds__(256, 4)
void cl_main(const float* __restrict__ x, const float* __restrict__ invn,
             float* __restrict__ denom_g, float* __restrict__ intra_g) {
    __shared__ float As[64][64];   // [k][row]  16 KB
    __shared__ float Bs[64][64];   // [k][col]  16 KB

    const int blk = blockIdx.x;
    const int quarter = blk & 3;
    const int rt = (blk >> 2) & 31;
    const int b = blk >> 7;
    const int rbase = rt << 6;
    const float* __restrict__ xb = x + (size_t)b * MM * DD;
    const float* __restrict__ invb = invn + b * MM;
    const int tid = threadIdx.x;

    // staging assignment: thread covers row (tid&63), k-span [(tid>>6)*16, +16)
    const int sr = tid & 63;
    const int skb = (tid >> 6) << 4;
    const int arow = rbase + sr;
    const float ainv = (arow < MM) ? invb[arow] : 0.0f;
    const float* __restrict__ asrc = xb + (size_t)(arow < MM ? arow : 0) * DD;

    const int tx = tid & 15, ty = tid >> 4;
    int rowcls[4];
    #pragma unroll
    for (int rr = 0; rr < 4; ++rr) rowcls[rr] = (rbase + (ty << 2) + rr) / KK;
    float denoms[4] = {0.f, 0.f, 0.f, 0.f};
    float intras[4] = {0.f, 0.f, 0.f, 0.f};

    for (int ct = 0; ct < 8; ++ct) {
        const int cbase = ((quarter << 3) + ct) << 6;
        const int bcol = cbase + sr;
        const float binv = (bcol < MM) ? invb[bcol] : 0.0f;
        const float* __restrict__ bsrc = xb + (size_t)(bcol < MM ? bcol : 0) * DD;

        float acc[4][4];
        #pragma unroll
        for (int i = 0; i < 4; ++i) {
            #pragma unroll
            for (int j = 0; j < 4; ++j) acc[i][j] = 0.0f;
        }

        #pragma unroll 1
        for (int kc = 0; kc < 4; ++kc) {
            __syncthreads();
            const float* sa = asrc + (kc << 6) + skb;
            const float* sb = bsrc + (kc << 6) + skb;
            #pragma unroll
            for (int q = 0; q < 16; ++q) As[skb + q][sr] = sa[q] * ainv;
            #pragma unroll
            for (int q = 0; q < 16; ++q) Bs[skb + q][sr] = sb[q] * binv;
            __syncthreads();
            #pragma unroll 16
            for (int kk = 0; kk < 64; ++kk) {
                const float4 a4 = *(const float4*)&As[kk][ty << 2];
                const float4 b4 = *(const float4*)&Bs[kk][tx << 2];
                const float av[4] = {a4.x, a4.y, a4.z, a4.w};
                const float bv[4] = {b4.x, b4.y, b4.z, b4.w};
                #pragma unroll
                for (int i = 0; i < 4; ++i) {
                    #pragma unroll
                    for (int j = 0; j < 4; ++j) acc[i][j] += av[i] * bv[j];
                }
            }
        }

        // epilogue for this 64x64 tile: exp-sum (diagonal skipped exactly)
        // and same-class sim sum
        #pragma unroll
        for (int rr = 0; rr < 4; ++rr) {
            const int row = rbase + (ty << 2) + rr;
            const bool rok = row < MM;
            #pragma unroll
            for (int cc = 0; cc < 4; ++cc) {
                const int col = cbase + (tx << 2) + cc;
                const bool ok = rok && (col < MM) && (row != col);
                const float sim = acc[rr][cc] * TINV;
                denoms[rr] += ok ? __expf(sim) : 0.0f;
                intras[rr] += (ok && (col / KK == rowcls[rr])) ? sim : 0.0f;
            }
        }
    }

    // reduce across tx (lane bits 0..3), then one atomic per row per array
    #pragma unroll
    for (int rr = 0; rr < 4; ++rr) {
        #pragma unroll
        for (int o = 8; o >= 1; o >>= 1) {
            denoms[rr] += __shfl_xor(denoms[rr], o, 64);
            intras[rr] += __shfl_xor(intras[rr], o, 64);
        }
    }
    if (tx == 0) {
        #pragma unroll
        for (int rr = 0; rr < 4; ++rr) {
            const int row = rbase + (ty << 2) + rr;
            if (row < MM) {
                atomicAdd(&denom_g[b * MM + row], denoms[rr]);
                atomicAdd(&intra_g[b * MM + row], intras[rr]);
            }
        }
    }
}

// ---------------- kernel 3: log + final reduction + scale ----------------
__global__ void finalize_kernel(const float* __restrict__ denom_g,
                                const float* __restrict__ intra_g,
                                float* __restrict__ out) {
    __shared__ float red[4];
    float s = 0.0f;
    for (int i = threadIdx.x; i < BB * MM; i += 256)
        s += logf(denom_g[i]) - intra_g[i] * (1.0f / (KK - 1));
    #pragma unroll
    for (int o = 32; o >= 1; o >>= 1) s += __shfl_xor(s, o, 64);
    if ((threadIdx.x & 63) == 0) red[threadIdx.x >> 6] = s;
    __syncthreads();
    if (threadIdx.x == 0) out[0] = (red[0] + red[1] + red[2] + red[3]) * LOSS_SCALE;
}

extern "C" void kernel_launch(void* const* d_in, const int* in_sizes, int n_in,
                              void* d_out, int out_size, void* d_ws, size_t ws_size,
                              hipStream_t stream) {
    const float* x = (const float*)d_in[0];
    float* out = (float*)d_out;
    float* denom_g = (float*)d_ws;             // 16000 floats
    float* intra_g = denom_g + BB * MM;        // 16000 floats
    float* invn = intra_g + BB * MM;           // 16000 floats

    hipMemsetAsync(d_ws, 0, (size_t)2 * BB * MM * sizeof(float), stream);
    norm_kernel<<<BB * MM / 4, 256, 0, stream>>>(x, invn);
    cl_main<<<1024, 256, 0, stream>>>(x, invn, denom_g, intra_g);
    finalize_kernel<<<1, 256, 0, stream>>>(denom_g, intra_g, out);
}

// Round 2
// 130.525 us; speedup vs baseline: 2.6650x; 2.6650x over previous
//
#include <hip/hip_runtime.h>
#include <math.h>

#define BB 8
#define NN 100
#define KK 20
#define DD 256
#define MM 2000                    // NN*KK anchors per batch
#define MP 2048                    // padded rows per batch
#define TINV 10.0f                 // 1/TEMP
#define LOSS_SCALE 1.953125e-7f    // ALPHA / (B_NORM*N*K*D) = 0.1/512000

typedef __bf16 bf16x8 __attribute__((ext_vector_type(8)));
typedef float floatx4 __attribute__((ext_vector_type(4)));

__device__ __forceinline__ ushort f2bf(float f) {
    unsigned int u = __float_as_uint(f);
    u += 0x7fffu + ((u >> 16) & 1u);   // round-to-nearest-even
    return (ushort)(u >> 16);
}

// ---------------- kernel 1: normalize rows, convert to bf16, zero-pad ----------------
// one wave per padded row (16384 rows); 64 lanes x float4
__global__ void norm_bf16(const float* __restrict__ x, ushort* __restrict__ xb) {
    const int rg = blockIdx.x * 4 + (threadIdx.x >> 6);   // 0..16383
    const int lane = threadIdx.x & 63;
    const int b = rg >> 11;
    const int r = rg & (MP - 1);
    ushort4 outv = make_ushort4(0, 0, 0, 0);
    if (r < MM) {   // wave-uniform branch
        const float4 v = ((const float4*)(x + ((size_t)(b * MM + r)) * DD))[lane];
        float s = v.x * v.x + v.y * v.y + v.z * v.z + v.w * v.w;
        #pragma unroll
        for (int o = 32; o >= 1; o >>= 1) s += __shfl_xor(s, o, 64);
        const float inv = 1.0f / sqrtf(s);
        outv.x = f2bf(v.x * inv);
        outv.y = f2bf(v.y * inv);
        outv.z = f2bf(v.z * inv);
        outv.w = f2bf(v.w * inv);
    }
    ((ushort4*)(xb + (size_t)rg * DD))[lane] = outv;
}

// ---------------- kernel 2: MFMA Gram + fused exp/intra epilogue ----------------
// grid = 8 batches x 16 rowtiles x 16 coltiles = 2048 blocks, 256 threads.
// Block tile 128x128; 4 waves in 2x2, each wave 64x64 = 4x4 MFMA(16x16x32) tiles.
// K=256 staged in 4 chunks of 64 bf16; LDS row stride 72 (conflict-free b128 reads).
#define SAP 72
__global__ __launch_bounds__(256)
void cl_mfma(const ushort* __restrict__ xb,
             float* __restrict__ denom_g, float* __restrict__ intra_g) {
    __shared__ __align__(16) ushort As[128 * SAP];
    __shared__ __align__(16) ushort Bs[128 * SAP];

    const int blk = blockIdx.x;
    const int b = blk >> 8;
    const int rbase = ((blk >> 4) & 15) << 7;
    const int cbase = (blk & 15) << 7;
    const ushort* __restrict__ xbb = xb + (size_t)b * MP * DD;

    const int tid = threadIdx.x;
    // staging: thread covers row sr (0..127), 32-element half sh (0 or 32)
    const int sr = tid >> 1;
    const int sh = (tid & 1) << 5;
    const ushort* ag = xbb + (size_t)(rbase + sr) * DD + sh;
    const ushort* bg = xbb + (size_t)(cbase + sr) * DD + sh;
    ushort* al = As + sr * SAP + sh;
    ushort* bl = Bs + sr * SAP + sh;

    // compute-side ids
    const int lane = tid & 63;
    const int w = tid >> 6;
    const int wr = (w >> 1) << 6;   // wave row offset within block tile
    const int wc = (w & 1) << 6;    // wave col offset
    const int tx = lane & 15;
    const int quad = lane >> 4;

    floatx4 acc[4][4];
    #pragma unroll
    for (int mt = 0; mt < 4; ++mt)
        #pragma unroll
        for (int nt = 0; nt < 4; ++nt)
            acc[mt][nt] = (floatx4){0.f, 0.f, 0.f, 0.f};

    #pragma unroll 1
    for (int kc = 0; kc < 4; ++kc) {
        __syncthreads();
        const ushort* agk = ag + (kc << 6);
        const ushort* bgk = bg + (kc << 6);
        #pragma unroll
        for (int s = 0; s < 4; ++s)
            *(uint4*)(al + (s << 3)) = *(const uint4*)(agk + (s << 3));
        #pragma unroll
        for (int s = 0; s < 4; ++s)
            *(uint4*)(bl + (s << 3)) = *(const uint4*)(bgk + (s << 3));
        __syncthreads();

        #pragma unroll
        for (int ks = 0; ks < 2; ++ks) {
            bf16x8 af[4], bf[4];
            #pragma unroll
            for (int mt = 0; mt < 4; ++mt)
                af[mt] = *(const bf16x8*)(As + (wr + (mt << 4) + tx) * SAP + (ks << 5) + (quad << 3));
            #pragma unroll
            for (int nt = 0; nt < 4; ++nt)
                bf[nt] = *(const bf16x8*)(Bs + (wc + (nt << 4) + tx) * SAP + (ks << 5) + (quad << 3));
            #pragma unroll
            for (int mt = 0; mt < 4; ++mt)
                #pragma unroll
                for (int nt = 0; nt < 4; ++nt)
                    acc[mt][nt] = __builtin_amdgcn_mfma_f32_16x16x32_bf16(af[mt], bf[nt], acc[mt][nt], 0, 0, 0);
        }
    }

    // epilogue: sim = acc/T; denom += exp(sim) (skip diagonal & padded cols);
    // intra += sim for same-class cols. C/D layout: col=lane&15, row=quad*4+reg.
    int colv[4], colcls[4];
    bool colok[4];
    #pragma unroll
    for (int nt = 0; nt < 4; ++nt) {
        const int c = cbase + wc + (nt << 4) + tx;
        colv[nt] = c;
        colok[nt] = c < MM;
        colcls[nt] = c / KK;
    }
    #pragma unroll
    for (int mt = 0; mt < 4; ++mt) {
        #pragma unroll
        for (int i = 0; i < 4; ++i) {
            const int row = rbase + wr + (mt << 4) + (quad << 2) + i;
            const int rcls = row / KK;
            float de = 0.f, it = 0.f;
            #pragma unroll
            for (int nt = 0; nt < 4; ++nt) {
                const float sim = acc[mt][nt][i] * TINV;
                const bool ok = colok[nt] && (colv[nt] != row);
                de += ok ? __expf(sim) : 0.0f;
                it += (ok && (colcls[nt] == rcls)) ? sim : 0.0f;
            }
            #pragma unroll
            for (int o = 8; o >= 1; o >>= 1) {
                de += __shfl_xor(de, o, 64);
                it += __shfl_xor(it, o, 64);
            }
            if (tx == 0) {
                atomicAdd(&denom_g[b * MP + row], de);
                atomicAdd(&intra_g[b * MP + row], it);
            }
        }
    }
}

// ---------------- kernel 3: log + final reduction + scale ----------------
__global__ void finalize_kernel(const float* __restrict__ denom_g,
                                const float* __restrict__ intra_g,
                                float* __restrict__ out) {
    __shared__ float red[4];
    float s = 0.0f;
    for (int b = 0; b < BB; ++b) {
        const float* dn = denom_g + b * MP;
        const float* in_ = intra_g + b * MP;
        for (int r = threadIdx.x; r < MM; r += 256)
            s += logf(dn[r]) - in_[r] * (1.0f / (KK - 1));
    }
    #pragma unroll
    for (int o = 32; o >= 1; o >>= 1) s += __shfl_xor(s, o, 64);
    if ((threadIdx.x & 63) == 0) red[threadIdx.x >> 6] = s;
    __syncthreads();
    if (threadIdx.x == 0) out[0] = (red[0] + red[1] + red[2] + red[3]) * LOSS_SCALE;
}

extern "C" void kernel_launch(void* const* d_in, const int* in_sizes, int n_in,
                              void* d_out, int out_size, void* d_ws, size_t ws_size,
                              hipStream_t stream) {
    const float* x = (const float*)d_in[0];
    float* out = (float*)d_out;
    float* denom_g = (float*)d_ws;                 // 8*2048 floats
    float* intra_g = denom_g + BB * MP;            // 8*2048 floats
    ushort* xb = (ushort*)(intra_g + BB * MP);     // 8*2048*256 bf16 = 8 MB

    hipMemsetAsync(d_ws, 0, (size_t)2 * BB * MP * sizeof(float), stream);
    norm_bf16<<<BB * MP / 4, 256, 0, stream>>>(x, xb);
    cl_mfma<<<BB * 16 * 16, 256, 0, stream>>>(xb, denom_g, intra_g);
    finalize_kernel<<<1, 256, 0, stream>>>(denom_g, intra_g, out);
}

// Round 3
// 103.950 us; speedup vs baseline: 3.3463x; 1.2556x over previous
//
#include <hip/hip_runtime.h>
#include <math.h>

#define BB 8
#define NN 100
#define KK 20
#define DD 256
#define MM 2000                    // NN*KK anchors per batch
#define MP 2048                    // padded rows per batch
#define TINV 10.0f                 // 1/TEMP
#define LOSS_SCALE 1.953125e-7f    // ALPHA / (B_NORM*N*K*D) = 0.1/512000

typedef __bf16 bf16x8 __attribute__((ext_vector_type(8)));
typedef float floatx4 __attribute__((ext_vector_type(4)));
typedef __attribute__((address_space(1))) const ushort GUshort;
typedef __attribute__((address_space(3))) ushort LUshort;

__device__ __forceinline__ ushort f2bf(float f) {
    unsigned int u = __float_as_uint(f);
    u += 0x7fffu + ((u >> 16) & 1u);   // round-to-nearest-even
    return (ushort)(u >> 16);
}

// ---------------- kernel 1: normalize rows, convert to bf16, zero-pad ----------------
__global__ void norm_bf16(const float* __restrict__ x, ushort* __restrict__ xb) {
    const int rg = blockIdx.x * 4 + (threadIdx.x >> 6);   // 0..16383
    const int lane = threadIdx.x & 63;
    const int b = rg >> 11;
    const int r = rg & (MP - 1);
    ushort4 outv = make_ushort4(0, 0, 0, 0);
    if (r < MM) {   // wave-uniform branch
        const float4 v = ((const float4*)(x + ((size_t)(b * MM + r)) * DD))[lane];
        float s = v.x * v.x + v.y * v.y + v.z * v.z + v.w * v.w;
        #pragma unroll
        for (int o = 32; o >= 1; o >>= 1) s += __shfl_xor(s, o, 64);
        const float inv = 1.0f / sqrtf(s);
        outv.x = f2bf(v.x * inv);
        outv.y = f2bf(v.y * inv);
        outv.z = f2bf(v.z * inv);
        outv.w = f2bf(v.w * inv);
    }
    ((ushort4*)(xb + (size_t)rg * DD))[lane] = outv;
}

// ---------------- kernel 2: symmetric MFMA Gram + fused exp/intra epilogue ----------------
// grid = 8 batches x 136 upper-tri tile pairs (16x16 grid of 128x128 tiles).
// LDS: unpadded 128 rows x 64 ushorts, granule-XOR-swizzled:
//   granule g (8 ushorts) of row r lives at position g^(r&7) -> conflict-free
//   b128 frag reads AND lane-contiguous global_load_lds staging.
__global__ __launch_bounds__(256)
void cl_mfma(const ushort* __restrict__ xb,
             float* __restrict__ denom_g, float* __restrict__ intra_g) {
    __shared__ __align__(16) ushort As[128 * 64];
    __shared__ __align__(16) ushort Bs[128 * 64];

    // decode block -> (batch, upper-tri tile pair)
    const int b = blockIdx.x / 136;
    int rem = blockIdx.x - b * 136;
    int ti = 0;
    while (rem >= 16 - ti) { rem -= 16 - ti; ++ti; }
    const int tj = ti + rem;
    const int rbase = ti << 7;
    const int cbase = tj << 7;
    const bool offdiag = (ti != tj);
    const ushort* __restrict__ xbb = xb + (size_t)b * MP * DD;

    const int tid = threadIdx.x;
    const int lane = tid & 63;
    const int w = tid >> 6;
    const int wr = (w >> 1) << 6;   // wave row offset within 128-tile
    const int wc = (w & 1) << 6;    // wave col offset
    const int tx = lane & 15;
    const int tx7 = tx & 7;
    const int quad = lane >> 4;

    // staging lane roles: 8 rows x 8 granule-slots per instruction
    const int srow = lane >> 3;          // row within 8-row chunk
    const int sg = (lane & 7) ^ srow;    // logical granule this slot holds

    floatx4 acc[4][4];
    #pragma unroll
    for (int mt = 0; mt < 4; ++mt)
        #pragma unroll
        for (int nt = 0; nt < 4; ++nt)
            acc[mt][nt] = (floatx4){0.f, 0.f, 0.f, 0.f};

    #pragma unroll 1
    for (int kc = 0; kc < 4; ++kc) {
        __syncthreads();
        #pragma unroll
        for (int q = 0; q < 4; ++q) {
            const int R = ((w << 2) + q) << 3;            // 8-row chunk base
            const size_t koff = (kc << 6) + (sg << 3);
            __builtin_amdgcn_global_load_lds(
                (GUshort*)(xbb + (size_t)(rbase + R + srow) * DD + koff),
                (LUshort*)(As + R * 64), 16, 0, 0);
            __builtin_amdgcn_global_load_lds(
                (GUshort*)(xbb + (size_t)(cbase + R + srow) * DD + koff),
                (LUshort*)(Bs + R * 64), 16, 0, 0);
        }
        __syncthreads();

        #pragma unroll
        for (int ks = 0; ks < 2; ++ks) {
            const int g = (ks << 2) + quad;          // logical granule
            const int gp = (g ^ tx7) << 3;           // swizzled ushort offset
            bf16x8 af[4], bf[4];
            #pragma unroll
            for (int mt = 0; mt < 4; ++mt)
                af[mt] = *(const bf16x8*)(As + (wr + (mt << 4) + tx) * 64 + gp);
            #pragma unroll
            for (int nt = 0; nt < 4; ++nt)
                bf[nt] = *(const bf16x8*)(Bs + (wc + (nt << 4) + tx) * 64 + gp);
            #pragma unroll
            for (int mt = 0; mt < 4; ++mt)
                #pragma unroll
                for (int nt = 0; nt < 4; ++nt)
                    acc[mt][nt] = __builtin_amdgcn_mfma_f32_16x16x32_bf16(af[mt], bf[nt], acc[mt][nt], 0, 0, 0);
        }
    }

    // epilogue. C/D layout: col=lane&15, row=quad*4+reg.
    int colv[4], colcls[4];
    bool colok[4];
    #pragma unroll
    for (int nt = 0; nt < 4; ++nt) {
        const int c = cbase + wc + (nt << 4) + tx;
        colv[nt] = c;
        colok[nt] = c < MM;
        colcls[nt] = c / KK;
    }
    float de_c[4] = {0.f, 0.f, 0.f, 0.f};
    float it_c[4] = {0.f, 0.f, 0.f, 0.f};

    #pragma unroll
    for (int mt = 0; mt < 4; ++mt) {
        #pragma unroll
        for (int i = 0; i < 4; ++i) {
            const int row = rbase + wr + (mt << 4) + (quad << 2) + i;
            const int rcls = row / KK;
            float de = 0.f, it = 0.f;
            #pragma unroll
            for (int nt = 0; nt < 4; ++nt) {
                const float sim = acc[mt][nt][i] * TINV;
                const bool ok = colok[nt] && (colv[nt] != row);
                const float e = ok ? __expf(sim) : 0.0f;
                const float sv = (ok && (colcls[nt] == rcls)) ? sim : 0.0f;
                de += e;
                it += sv;
                de_c[nt] += e;   // col-side (used only when offdiag; rows<MM there)
                it_c[nt] += sv;
            }
            #pragma unroll
            for (int o = 8; o >= 1; o >>= 1) {
                de += __shfl_xor(de, o, 64);
                it += __shfl_xor(it, o, 64);
            }
            if (tx == 0) {
                atomicAdd(&denom_g[b * MP + row], de);
                atomicAdd(&intra_g[b * MP + row], it);
            }
        }
    }

    if (offdiag) {
        #pragma unroll
        for (int nt = 0; nt < 4; ++nt) {
            de_c[nt] += __shfl_xor(de_c[nt], 16, 64);
            de_c[nt] += __shfl_xor(de_c[nt], 32, 64);
            it_c[nt] += __shfl_xor(it_c[nt], 16, 64);
            it_c[nt] += __shfl_xor(it_c[nt], 32, 64);
        }
        if (quad == 0) {
            #pragma unroll
            for (int nt = 0; nt < 4; ++nt) {
                if (colok[nt]) {
                    atomicAdd(&denom_g[b * MP + colv[nt]], de_c[nt]);
                    atomicAdd(&intra_g[b * MP + colv[nt]], it_c[nt]);
                }
            }
        }
    }
}

// ---------------- kernel 3: log + final reduction, parallel + atomic ----------------
__global__ void finalize_kernel(const float* __restrict__ denom_g,
                                const float* __restrict__ intra_g,
                                float* __restrict__ out) {
    const int i = blockIdx.x * 256 + threadIdx.x;
    float s = 0.0f;
    if (i < BB * MM) {
        const int b = i / MM;
        const int r = i - b * MM;
        s = logf(denom_g[b * MP + r]) - intra_g[b * MP + r] * (1.0f / (KK - 1));
    }
    #pragma unroll
    for (int o = 32; o >= 1; o >>= 1) s += __shfl_xor(s, o, 64);
    __shared__ float red[4];
    if ((threadIdx.x & 63) == 0) red[threadIdx.x >> 6] = s;
    __syncthreads();
    if (threadIdx.x == 0)
        atomicAdd(out, (red[0] + red[1] + red[2] + red[3]) * LOSS_SCALE);
}

extern "C" void kernel_launch(void* const* d_in, const int* in_sizes, int n_in,
                              void* d_out, int out_size, void* d_ws, size_t ws_size,
                              hipStream_t stream) {
    const float* x = (const float*)d_in[0];
    float* out = (float*)d_out;
    float* denom_g = (float*)d_ws;                 // 8*2048 floats
    float* intra_g = denom_g + BB * MP;            // 8*2048 floats
    ushort* xb = (ushort*)(intra_g + BB * MP);     // 8*2048*256 bf16 = 8 MB

    hipMemsetAsync(d_ws, 0, (size_t)2 * BB * MP * sizeof(float), stream);
    hipMemsetAsync(d_out, 0, sizeof(float), stream);
    norm_bf16<<<BB * MP / 4, 256, 0, stream>>>(x, xb);
    cl_mfma<<<BB * 136, 256, 0, stream>>>(xb, denom_g, intra_g);
    finalize_kernel<<<(BB * MM + 255) / 256, 256, 0, stream>>>(denom_g, intra_g, out);
}